// Round 2
// baseline (847.436 us; speedup 1.0000x reference)
//
#include <hip/hip_runtime.h>
#include <math.h>

#define NB 64
#define NT 2000
#define NE 512
#define ND 1024
#define NA 256
#define NFF 32
#define NK 31
#define NPAD 15

// ---------------------------------------------------------------------------
// Kernel 1: dec_proj[b][a] = sum_d decoder_state[b][d] * W_dec[d][a]
// grid(4, NB), block 64: block (ac,b) computes cols [ac*64, ac*64+64)
// ---------------------------------------------------------------------------
__global__ __launch_bounds__(64) void dec_proj_kernel(
    const float* __restrict__ dec, const float* __restrict__ W_dec,
    float* __restrict__ dec_proj)
{
    const int b = blockIdx.y;
    const int col = blockIdx.x * 64 + threadIdx.x;
    const float* drow = dec + (size_t)b * ND;
    float a0 = 0.f, a1 = 0.f, a2 = 0.f, a3 = 0.f;
    for (int d = 0; d < ND; d += 4) {
        a0 += drow[d + 0] * W_dec[(size_t)(d + 0) * NA + col];
        a1 += drow[d + 1] * W_dec[(size_t)(d + 1) * NA + col];
        a2 += drow[d + 2] * W_dec[(size_t)(d + 2) * NA + col];
        a3 += drow[d + 3] * W_dec[(size_t)(d + 3) * NA + col];
    }
    dec_proj[b * NA + col] = (a0 + a1) + (a2 + a3);
}

// ---------------------------------------------------------------------------
// Kernel 2: fold conv + loc projection: Wc[k][a] = sum_f conv_w[f][k]*W_loc[f][a]
// 1 block, 256 threads (thread = column a)
// ---------------------------------------------------------------------------
__global__ __launch_bounds__(256) void wc_kernel(
    const float* __restrict__ conv_w, const float* __restrict__ W_loc,
    float* __restrict__ Wc)
{
    const int a = threadIdx.x;
    for (int k = 0; k < NK; ++k) {
        float acc = 0.f;
        #pragma unroll
        for (int f = 0; f < NFF; ++f)
            acc += conv_w[f * NK + k] * W_loc[f * NA + a];
        Wc[k * NA + a] = acc;
    }
}

// ---------------------------------------------------------------------------
// Kernel 3: energy[b][t] = v . tanh(enc[b,t,:]@W_enc + dec_proj[b,:] + loc)
//   loc[t][a] = sum_k prev[b, t+k-15] * Wc[k][a]
// Tile: 64 rows (t) x 256 cols (a) per block; K-chunked GEMM through LDS.
// block 256 = (ty in [0,8)) x (tx in [0,32)); thread: 8 rows x 8 cols.
// grid(32, NB).
// ---------------------------------------------------------------------------
__global__ __launch_bounds__(256) void energy_kernel(
    const float* __restrict__ enc, const float* __restrict__ prev,
    const int* __restrict__ mask, const float* __restrict__ W_enc,
    const float* __restrict__ dec_proj, const float* __restrict__ Wc,
    const float* __restrict__ v_w, float* __restrict__ energy)
{
    __shared__ __align__(16) float A_lds[64][36];   // [row][k], pad 36 (144B rows, 16B aligned)
    __shared__ __align__(16) float B_lds[32][260];  // [k][col], pad 260 (1040B rows, 16B aligned)
    __shared__ float prev_s[96];
    __shared__ float dec_s[NA];
    __shared__ float v_s[NA];

    const int tid = threadIdx.x;
    const int b = blockIdx.y;
    const int t0 = blockIdx.x * 64;
    const int ty = tid >> 5;   // 0..7  -> rows ty*8 .. ty*8+7
    const int tx = tid & 31;   // 0..31 -> cols tx*2 + 64*c + j

    dec_s[tid] = dec_proj[b * NA + tid];
    v_s[tid] = v_w[tid];
    if (tid < 96) {
        int gt = t0 - NPAD + tid;
        prev_s[tid] = (gt >= 0 && gt < NT) ? prev[(size_t)b * NT + gt] : 0.f;
    }

    float acc[8][8];
    #pragma unroll
    for (int i = 0; i < 8; ++i)
        #pragma unroll
        for (int j = 0; j < 8; ++j) acc[i][j] = 0.f;

    for (int ec = 0; ec < NE; ec += 32) {
        // stage A tile: 64 rows x 32 k  (2 float4 per thread)
        #pragma unroll
        for (int i = 0; i < 2; ++i) {
            int fid = tid + 256 * i;
            int row = fid >> 3, q = fid & 7;
            int t = t0 + row;
            float4 val = make_float4(0.f, 0.f, 0.f, 0.f);
            if (t < NT)
                val = *(const float4*)&enc[((size_t)b * NT + t) * NE + ec + q * 4];
            *(float4*)&A_lds[row][q * 4] = val;
        }
        // stage B tile: 32 k x 256 cols (8 float4 per thread)
        #pragma unroll
        for (int i = 0; i < 8; ++i) {
            int fid = tid + 256 * i;
            int k = fid >> 6, c4 = fid & 63;
            *(float4*)&B_lds[k][c4 * 4] = *(const float4*)&W_enc[(size_t)(ec + k) * NA + c4 * 4];
        }
        __syncthreads();

        #pragma unroll
        for (int k = 0; k < 32; k += 2) {
            float2 a2[8];
            #pragma unroll
            for (int i = 0; i < 8; ++i)
                a2[i] = *(const float2*)&A_lds[ty * 8 + i][k];
            float2 b0[4], b1[4];
            #pragma unroll
            for (int c = 0; c < 4; ++c) {
                b0[c] = *(const float2*)&B_lds[k][tx * 2 + 64 * c];
                b1[c] = *(const float2*)&B_lds[k + 1][tx * 2 + 64 * c];
            }
            #pragma unroll
            for (int i = 0; i < 8; ++i) {
                #pragma unroll
                for (int c = 0; c < 4; ++c) {
                    acc[i][2 * c + 0] += a2[i].x * b0[c].x;
                    acc[i][2 * c + 1] += a2[i].x * b0[c].y;
                    acc[i][2 * c + 0] += a2[i].y * b1[c].x;
                    acc[i][2 * c + 1] += a2[i].y * b1[c].y;
                }
            }
        }
        __syncthreads();
    }

    // column indices this thread owns
    int a_idx[8];
    #pragma unroll
    for (int cc = 0; cc < 8; ++cc)
        a_idx[cc] = tx * 2 + 64 * (cc >> 1) + (cc & 1);

    // add location term: acc[i][cc] += sum_k prev_s[r+k] * Wc[k][a]
    for (int k = 0; k < NK; ++k) {
        float w[8];
        #pragma unroll
        for (int cc = 0; cc < 8; ++cc) w[cc] = Wc[k * NA + a_idx[cc]];
        #pragma unroll
        for (int i = 0; i < 8; ++i) {
            float pv = prev_s[ty * 8 + i + k];
            #pragma unroll
            for (int cc = 0; cc < 8; ++cc) acc[i][cc] += pv * w[cc];
        }
    }

    float dv[8], vv[8];
    #pragma unroll
    for (int cc = 0; cc < 8; ++cc) { dv[cc] = dec_s[a_idx[cc]]; vv[cc] = v_s[a_idx[cc]]; }

    #pragma unroll
    for (int i = 0; i < 8; ++i) {
        const int t = t0 + ty * 8 + i;
        float p = 0.f;
        #pragma unroll
        for (int cc = 0; cc < 8; ++cc)
            p += tanhf(acc[i][cc] + dv[cc]) * vv[cc];
        // reduce over the 32 lanes (tx) sharing this row
        #pragma unroll
        for (int off = 16; off >= 1; off >>= 1)
            p += __shfl_xor(p, off, 32);
        if (tx == 0 && t < NT) {
            float e = (mask[(size_t)b * NT + t] == 0) ? -1e9f : p;
            energy[(size_t)b * NT + t] = e;
        }
    }
}

// ---------------------------------------------------------------------------
// Kernel 4: softmax over T per batch (in-place on the attn region of d_out),
// plus zero the context region (so kernel 5 can atomicAdd).
// grid NB, block 256.
// ---------------------------------------------------------------------------
__global__ __launch_bounds__(256) void softmax_kernel(
    float* attn_io, float* ctx)
{
    __shared__ float e_s[NT];
    __shared__ float wred[4];
    __shared__ float wsum[4];
    const int b = blockIdx.x;
    const int tid = threadIdx.x;

    float m = -1e30f;
    for (int t = tid; t < NT; t += 256) {
        float v = attn_io[(size_t)b * NT + t];
        e_s[t] = v;
        m = fmaxf(m, v);
    }
    #pragma unroll
    for (int off = 32; off >= 1; off >>= 1)
        m = fmaxf(m, __shfl_xor(m, off, 64));
    if ((tid & 63) == 0) wred[tid >> 6] = m;
    __syncthreads();
    m = fmaxf(fmaxf(wred[0], wred[1]), fmaxf(wred[2], wred[3]));

    float s = 0.f;
    for (int t = tid; t < NT; t += 256) {
        float v = expf(e_s[t] - m);
        e_s[t] = v;
        s += v;
    }
    #pragma unroll
    for (int off = 32; off >= 1; off >>= 1)
        s += __shfl_xor(s, off, 64);
    if ((tid & 63) == 0) wsum[tid >> 6] = s;
    __syncthreads();
    s = wsum[0] + wsum[1] + wsum[2] + wsum[3];

    const float inv = 1.f / s;
    for (int t = tid; t < NT; t += 256)
        attn_io[(size_t)b * NT + t] = e_s[t] * inv;

    // zero context row for this batch (dec_proj/Wc scratch lived here; done with it)
    for (int e = tid; e < NE; e += 256)
        ctx[(size_t)b * NE + e] = 0.f;
}

// ---------------------------------------------------------------------------
// Kernel 5: context[b][e] = sum_t attn[b][t] * enc[b][t][e]
// grid(8, NB): each block handles 250 t's; float2 per thread; atomicAdd.
// ---------------------------------------------------------------------------
__global__ __launch_bounds__(256) void context_kernel(
    const float* __restrict__ enc, const float* __restrict__ attn,
    float* __restrict__ ctx)
{
    __shared__ float at_s[250];
    const int b = blockIdx.y;
    const int tbase = blockIdx.x * 250;
    const int tid = threadIdx.x;

    if (tid < 250) at_s[tid] = attn[(size_t)b * NT + tbase + tid];
    __syncthreads();

    const float2* encp = (const float2*)(enc + ((size_t)b * NT + tbase) * NE);
    float ax = 0.f, ay = 0.f;
    #pragma unroll 4
    for (int t = 0; t < 250; ++t) {
        float2 v = encp[(size_t)t * (NE / 2) + tid];
        float a = at_s[t];
        ax += a * v.x;
        ay += a * v.y;
    }
    atomicAdd(&ctx[(size_t)b * NE + tid * 2 + 0], ax);
    atomicAdd(&ctx[(size_t)b * NE + tid * 2 + 1], ay);
}

// ---------------------------------------------------------------------------
extern "C" void kernel_launch(void* const* d_in, const int* in_sizes, int n_in,
                              void* d_out, int out_size, void* d_ws, size_t ws_size,
                              hipStream_t stream)
{
    const float* dec    = (const float*)d_in[0];
    const float* enc    = (const float*)d_in[1];
    const float* prev   = (const float*)d_in[2];
    const int*   mask   = (const int*)d_in[3];
    const float* conv_w = (const float*)d_in[4];
    const float* W_enc  = (const float*)d_in[5];
    const float* W_dec  = (const float*)d_in[6];
    const float* W_loc  = (const float*)d_in[7];
    const float* v_w    = (const float*)d_in[8];

    float* out  = (float*)d_out;
    float* ctx  = out;             // [B,E] = 32768 floats
    float* attn = out + NB * NE;   // [B,T] = 128000 floats

    // Scratch carved from d_out's context region (zeroed by softmax_kernel
    // AFTER energy_kernel has consumed it; stream order guarantees safety).
    float* dec_proj = ctx;                 // 16384 floats
    float* Wc       = ctx + NB * NA;       // 7936 floats (16384+7936 <= 32768)

    dim3 gA(4, NB);
    dec_proj_kernel<<<gA, 64, 0, stream>>>(dec, W_dec, dec_proj);
    wc_kernel<<<1, 256, 0, stream>>>(conv_w, W_loc, Wc);

    dim3 gB(32, NB);  // 32 t-chunks of 64 rows x 64 batches
    energy_kernel<<<gB, 256, 0, stream>>>(enc, prev, mask, W_enc,
                                          dec_proj, Wc, v_w, attn);

    softmax_kernel<<<NB, 256, 0, stream>>>(attn, ctx);

    dim3 gD(8, NB);
    context_kernel<<<gD, 256, 0, stream>>>(enc, attn, ctx);
}

// Round 4
// 563.932 us; speedup vs baseline: 1.5027x; 1.5027x over previous
//
#include <hip/hip_runtime.h>
#include <math.h>

#define NB 64
#define NT 2000
#define NE 512
#define ND 1024
#define NA 256
#define NFF 32
#define NK 31
#define NPAD 15

#define KC_N 17          // K chunks: 16 from enc (512) + 1 location/ext chunk
#define BKP 40           // padded bf16 row length (80 B = 20 words -> 2-way banks)
#define B_ALL_BYTES (KC_N * 256 * BKP * 2)        // 348160
#define DECPROJ_BYTES (NB * NA * 4)               // 65536
#define WS_NEEDED (B_ALL_BYTES + DECPROJ_BYTES)   // 413696

typedef unsigned short ushort_t;
typedef unsigned int uint_t;
typedef __attribute__((ext_vector_type(8))) short short8_t;
typedef __attribute__((ext_vector_type(4))) float f32x4_t;

__device__ inline ushort_t f2bf(float x) {   // RNE fp32 -> bf16
    uint_t u = __float_as_uint(x);
    uint_t r = u + 0x7FFFu + ((u >> 16) & 1u);
    return (ushort_t)(r >> 16);
}

__device__ inline float fast_tanh(float x) {
    float e = __expf(2.0f * x);                  // v_exp based; inf-safe
    return 1.0f - __fdividef(2.0f, e + 1.0f);
}

__device__ inline void gload16(const void* g, void* l) {
    __builtin_amdgcn_global_load_lds(
        (const __attribute__((address_space(1))) uint_t*)g,
        (__attribute__((address_space(3))) uint_t*)l, 16, 0, 0);
}

// ---------------------------------------------------------------------------
// pack_kernel: build B_all[kc][n][BKP] bf16, chunk-major so a K-step's tile is
// one contiguous 20 KB block (linear global_load_lds -> padded LDS layout).
//   kc<16 : B^T of W_enc  (col c<32 -> W_enc[kc*32+c][n], else 0-pad)
//   kc==16: Wc[c][n] = sum_f conv_w[f][c]*W_loc[f][n] for c<31, else 0
// ---------------------------------------------------------------------------
__global__ __launch_bounds__(256) void pack_kernel(
    const float* __restrict__ W_enc, const float* __restrict__ conv_w,
    const float* __restrict__ W_loc, ushort_t* __restrict__ B_all)
{
    const int kc = blockIdx.x;
    const int tid = threadIdx.x;
    if (kc < 16) {
        #pragma unroll
        for (int i = 0; i < 40; ++i) {
            int idx = i * 256 + tid;
            int c = idx >> 8, n = idx & 255;          // tid -> n: coalesced reads
            ushort_t v = 0;
            if (c < 32) v = f2bf(W_enc[(size_t)(kc * 32 + c) * NA + n]);
            B_all[((size_t)kc * 256 + n) * BKP + c] = v;
        }
    } else {
        #pragma unroll 4
        for (int i = 0; i < 40; ++i) {
            int idx = i * 256 + tid;
            int c = idx >> 8, n = idx & 255;
            float acc = 0.f;
            if (c < NK) {
                #pragma unroll
                for (int f = 0; f < NFF; ++f)
                    acc += conv_w[f * NK + c] * W_loc[f * NA + n];
            }
            B_all[((size_t)kc * 256 + n) * BKP + c] = f2bf(acc);
        }
    }
}

// ---------------------------------------------------------------------------
// dec_proj (atomic K-split): grid(4, NB), block 256. dec_proj must be 0-init.
// ---------------------------------------------------------------------------
__global__ __launch_bounds__(256) void dec_proj_atomic_kernel(
    const float* __restrict__ dec, const float* __restrict__ W_dec,
    float* __restrict__ dec_proj)
{
    const int b = blockIdx.y;
    const int d0 = blockIdx.x * 256;
    const int a = threadIdx.x;
    const float* dr = dec + (size_t)b * ND + d0;
    float acc = 0.f;
    #pragma unroll 4
    for (int d = 0; d < 256; ++d)
        acc += dr[d] * W_dec[(size_t)(d0 + d) * NA + a];
    atomicAdd(&dec_proj[b * NA + a], acc);
}

// ---------------------------------------------------------------------------
// energy_mfma: C[64 t x 256 a] per block via mfma_f32_16x16x32_bf16.
// K_ext = 544 (512 enc + 31 loc + 1 zero), 17 chunks of 32.
// 4 waves: wave w owns cols [w*64, w*64+64), all 64 rows; 4x4 16x16 frags.
// B staged from pre-packed global via global_load_lds (padded layout baked in);
// A reg-staged with fp32->bf16 convert (enc) or built from prev_s (kc==16).
// Epilogue: +dec, tanh, *v, row-reduce (shfl + LDS cross-wave), mask, store.
// ---------------------------------------------------------------------------
__global__ __launch_bounds__(256) void energy_mfma_kernel(
    const float* __restrict__ enc, const float* __restrict__ prev,
    const int* __restrict__ mask, const ushort_t* __restrict__ B_all,
    const float* __restrict__ dec_proj, const float* __restrict__ v_w,
    float* __restrict__ energy)
{
    __shared__ __align__(16) ushort_t A_s[64][BKP];       // 5120 B
    __shared__ __align__(16) ushort_t B_s[256 * BKP];     // 20480 B
    __shared__ float prev_s[96];
    __shared__ float dec_s[NA];
    __shared__ float v_s[NA];
    __shared__ float partial_s[4][64];

    const int tid = threadIdx.x;
    const int b = blockIdx.y;
    const int t0 = blockIdx.x * 64;
    const int wid = tid >> 6;
    const int lane = tid & 63;
    const int l15 = lane & 15;
    const int l4 = lane >> 4;

    dec_s[tid] = dec_proj[b * NA + tid];
    v_s[tid] = v_w[tid];
    if (tid < 96) {
        int gt = t0 - NPAD + tid;
        prev_s[tid] = (gt >= 0 && gt < NT) ? prev[(size_t)b * NT + gt] : 0.f;
    }

    f32x4_t acc[4][4];
    #pragma unroll
    for (int mi = 0; mi < 4; ++mi)
        #pragma unroll
        for (int ni = 0; ni < 4; ++ni)
            acc[mi][ni] = (f32x4_t){0.f, 0.f, 0.f, 0.f};

    const int arow = tid >> 2;        // 0..63
    const int akg = tid & 3;          // k-group of 8
    const int t_a = t0 + arow;

    for (int kc = 0; kc < KC_N; ++kc) {
        // ---- stage A tile [64][32] -> bf16 padded LDS ----
        float av[8];
        if (kc < 16) {
            if (t_a < NT) {
                const float4* ap = (const float4*)(enc + ((size_t)b * NT + t_a) * NE + kc * 32);
                float4 v0 = ap[akg * 2], v1 = ap[akg * 2 + 1];
                av[0] = v0.x; av[1] = v0.y; av[2] = v0.z; av[3] = v0.w;
                av[4] = v1.x; av[5] = v1.y; av[6] = v1.z; av[7] = v1.w;
            } else {
                #pragma unroll
                for (int j = 0; j < 8; ++j) av[j] = 0.f;
            }
        } else {
            #pragma unroll
            for (int j = 0; j < 8; ++j) {
                int kk = akg * 8 + j;
                av[j] = (kk < NK) ? prev_s[arow + kk] : 0.f;
            }
        }
        uint_t pk[4];
        #pragma unroll
        for (int j = 0; j < 4; ++j)
            pk[j] = (uint_t)f2bf(av[2 * j]) | ((uint_t)f2bf(av[2 * j + 1]) << 16);
        *(uint4*)&A_s[arow][akg * 8] = make_uint4(pk[0], pk[1], pk[2], pk[3]);

        // ---- stage B tile: 20 KB contiguous -> LDS via global_load_lds ----
        const char* gsrc = (const char*)B_all + (size_t)kc * (256 * BKP * 2);
        #pragma unroll
        for (int c = 0; c < 5; ++c) {
            int chunk = wid * 5 + c;
            gload16(gsrc + chunk * 1024 + lane * 16, (void*)&B_s[chunk * 512]);
        }
        __syncthreads();

        // ---- fragments + 16 MFMAs ----
        short8_t af[4], bf[4];
        #pragma unroll
        for (int mi = 0; mi < 4; ++mi)
            af[mi] = *(const short8_t*)&A_s[mi * 16 + l15][l4 * 8];
        #pragma unroll
        for (int ni = 0; ni < 4; ++ni)
            bf[ni] = *(const short8_t*)&B_s[(size_t)(wid * 64 + ni * 16 + l15) * BKP + l4 * 8];
        #pragma unroll
        for (int mi = 0; mi < 4; ++mi)
            #pragma unroll
            for (int ni = 0; ni < 4; ++ni)
                acc[mi][ni] = __builtin_amdgcn_mfma_f32_16x16x32_bf16(
                    af[mi], bf[ni], acc[mi][ni], 0, 0, 0);
        __syncthreads();
    }

    // ---- epilogue: tanh(val+dec)*v, reduce over a ----
    #pragma unroll
    for (int mi = 0; mi < 4; ++mi) {
        #pragma unroll
        for (int r = 0; r < 4; ++r) {
            float s = 0.f;
            #pragma unroll
            for (int ni = 0; ni < 4; ++ni) {
                int a = wid * 64 + ni * 16 + l15;
                s += fast_tanh(acc[mi][ni][r] + dec_s[a]) * v_s[a];
            }
            s += __shfl_xor(s, 1);
            s += __shfl_xor(s, 2);
            s += __shfl_xor(s, 4);
            s += __shfl_xor(s, 8);
            if (l15 == 0)
                partial_s[wid][mi * 16 + l4 * 4 + r] = s;
        }
    }
    __syncthreads();
    if (tid < 64) {
        int t = t0 + tid;
        if (t < NT) {
            float e = partial_s[0][tid] + partial_s[1][tid]
                    + partial_s[2][tid] + partial_s[3][tid];
            if (mask[(size_t)b * NT + t] == 0) e = -1e9f;
            energy[(size_t)b * NT + t] = e;
        }
    }
}

// ---------------------------------------------------------------------------
// Fallback fp32 kernels (used only if ws_size < WS_NEEDED)
// ---------------------------------------------------------------------------
__global__ __launch_bounds__(64) void dec_proj_kernel(
    const float* __restrict__ dec, const float* __restrict__ W_dec,
    float* __restrict__ dec_proj)
{
    const int b = blockIdx.y;
    const int col = blockIdx.x * 64 + threadIdx.x;
    const float* drow = dec + (size_t)b * ND;
    float a0 = 0.f, a1 = 0.f, a2 = 0.f, a3 = 0.f;
    for (int d = 0; d < ND; d += 4) {
        a0 += drow[d + 0] * W_dec[(size_t)(d + 0) * NA + col];
        a1 += drow[d + 1] * W_dec[(size_t)(d + 1) * NA + col];
        a2 += drow[d + 2] * W_dec[(size_t)(d + 2) * NA + col];
        a3 += drow[d + 3] * W_dec[(size_t)(d + 3) * NA + col];
    }
    dec_proj[b * NA + col] = (a0 + a1) + (a2 + a3);
}

__global__ __launch_bounds__(256) void wc_kernel(
    const float* __restrict__ conv_w, const float* __restrict__ W_loc,
    float* __restrict__ Wc)
{
    const int a = threadIdx.x;
    for (int k = 0; k < NK; ++k) {
        float acc = 0.f;
        #pragma unroll
        for (int f = 0; f < NFF; ++f)
            acc += conv_w[f * NK + k] * W_loc[f * NA + a];
        Wc[k * NA + a] = acc;
    }
}

__global__ __launch_bounds__(256) void energy_kernel(
    const float* __restrict__ enc, const float* __restrict__ prev,
    const int* __restrict__ mask, const float* __restrict__ W_enc,
    const float* __restrict__ dec_proj, const float* __restrict__ Wc,
    const float* __restrict__ v_w, float* __restrict__ energy)
{
    __shared__ __align__(16) float A_lds[64][36];
    __shared__ __align__(16) float B_lds[32][260];
    __shared__ float prev_s[96];
    __shared__ float dec_s[NA];
    __shared__ float v_s[NA];

    const int tid = threadIdx.x;
    const int b = blockIdx.y;
    const int t0 = blockIdx.x * 64;
    const int ty = tid >> 5;
    const int tx = tid & 31;

    dec_s[tid] = dec_proj[b * NA + tid];
    v_s[tid] = v_w[tid];
    if (tid < 96) {
        int gt = t0 - NPAD + tid;
        prev_s[tid] = (gt >= 0 && gt < NT) ? prev[(size_t)b * NT + gt] : 0.f;
    }

    float acc[8][8];
    #pragma unroll
    for (int i = 0; i < 8; ++i)
        #pragma unroll
        for (int j = 0; j < 8; ++j) acc[i][j] = 0.f;

    for (int ec = 0; ec < NE; ec += 32) {
        #pragma unroll
        for (int i = 0; i < 2; ++i) {
            int fid = tid + 256 * i;
            int row = fid >> 3, q = fid & 7;
            int t = t0 + row;
            float4 val = make_float4(0.f, 0.f, 0.f, 0.f);
            if (t < NT)
                val = *(const float4*)&enc[((size_t)b * NT + t) * NE + ec + q * 4];
            *(float4*)&A_lds[row][q * 4] = val;
        }
        #pragma unroll
        for (int i = 0; i < 8; ++i) {
            int fid = tid + 256 * i;
            int k = fid >> 6, c4 = fid & 63;
            *(float4*)&B_lds[k][c4 * 4] = *(const float4*)&W_enc[(size_t)(ec + k) * NA + c4 * 4];
        }
        __syncthreads();

        #pragma unroll
        for (int k = 0; k < 32; k += 2) {
            float2 a2[8];
            #pragma unroll
            for (int i = 0; i < 8; ++i)
                a2[i] = *(const float2*)&A_lds[ty * 8 + i][k];
            float2 b0[4], b1[4];
            #pragma unroll
            for (int c = 0; c < 4; ++c) {
                b0[c] = *(const float2*)&B_lds[k][tx * 2 + 64 * c];
                b1[c] = *(const float2*)&B_lds[k + 1][tx * 2 + 64 * c];
            }
            #pragma unroll
            for (int i = 0; i < 8; ++i) {
                #pragma unroll
                for (int c = 0; c < 4; ++c) {
                    acc[i][2 * c + 0] += a2[i].x * b0[c].x;
                    acc[i][2 * c + 1] += a2[i].x * b0[c].y;
                    acc[i][2 * c + 0] += a2[i].y * b1[c].x;
                    acc[i][2 * c + 1] += a2[i].y * b1[c].y;
                }
            }
        }
        __syncthreads();
    }

    int a_idx[8];
    #pragma unroll
    for (int cc = 0; cc < 8; ++cc)
        a_idx[cc] = tx * 2 + 64 * (cc >> 1) + (cc & 1);

    for (int k = 0; k < NK; ++k) {
        float w[8];
        #pragma unroll
        for (int cc = 0; cc < 8; ++cc) w[cc] = Wc[k * NA + a_idx[cc]];
        #pragma unroll
        for (int i = 0; i < 8; ++i) {
            float pv = prev_s[ty * 8 + i + k];
            #pragma unroll
            for (int cc = 0; cc < 8; ++cc) acc[i][cc] += pv * w[cc];
        }
    }

    float dv[8], vv[8];
    #pragma unroll
    for (int cc = 0; cc < 8; ++cc) { dv[cc] = dec_s[a_idx[cc]]; vv[cc] = v_s[a_idx[cc]]; }

    #pragma unroll
    for (int i = 0; i < 8; ++i) {
        const int t = t0 + ty * 8 + i;
        float p = 0.f;
        #pragma unroll
        for (int cc = 0; cc < 8; ++cc)
            p += tanhf(acc[i][cc] + dv[cc]) * vv[cc];
        #pragma unroll
        for (int off = 16; off >= 1; off >>= 1)
            p += __shfl_xor(p, off, 32);
        if (tx == 0 && t < NT) {
            float e = (mask[(size_t)b * NT + t] == 0) ? -1e9f : p;
            energy[(size_t)b * NT + t] = e;
        }
    }
}

// ---------------------------------------------------------------------------
// softmax over T per batch (in place) + zero ctx region for atomics.
// ---------------------------------------------------------------------------
__global__ __launch_bounds__(512) void softmax_kernel(
    float* attn_io, float* ctx)
{
    __shared__ float e_s[NT];
    __shared__ float wred[8];
    __shared__ float wsum[8];
    const int b = blockIdx.x;
    const int tid = threadIdx.x;

    float m = -1e30f;
    for (int t = tid; t < NT; t += 512) {
        float v = attn_io[(size_t)b * NT + t];
        e_s[t] = v;
        m = fmaxf(m, v);
    }
    #pragma unroll
    for (int off = 32; off >= 1; off >>= 1)
        m = fmaxf(m, __shfl_xor(m, off, 64));
    if ((tid & 63) == 0) wred[tid >> 6] = m;
    __syncthreads();
    m = wred[0];
    #pragma unroll
    for (int i = 1; i < 8; ++i) m = fmaxf(m, wred[i]);

    float s = 0.f;
    for (int t = tid; t < NT; t += 512) {
        float v = __expf(e_s[t] - m);
        e_s[t] = v;
        s += v;
    }
    #pragma unroll
    for (int off = 32; off >= 1; off >>= 1)
        s += __shfl_xor(s, off, 64);
    if ((tid & 63) == 0) wsum[tid >> 6] = s;
    __syncthreads();
    s = 0.f;
    #pragma unroll
    for (int i = 0; i < 8; ++i) s += wsum[i];

    const float inv = 1.f / s;
    for (int t = tid; t < NT; t += 512)
        attn_io[(size_t)b * NT + t] = e_s[t] * inv;

    if (tid < NE)
        ctx[(size_t)b * NE + tid] = 0.f;
}

// ---------------------------------------------------------------------------
// context: float4 per thread, 2 rows in flight. grid(8, NB), block 256.
// ---------------------------------------------------------------------------
__global__ __launch_bounds__(256) void context_kernel(
    const float* __restrict__ enc, const float* __restrict__ attn,
    float* __restrict__ ctx)
{
    __shared__ float at_s[250];
    const int b = blockIdx.y;
    const int tbase = blockIdx.x * 250;
    const int tid = threadIdx.x;

    if (tid < 250) at_s[tid] = attn[(size_t)b * NT + tbase + tid];
    __syncthreads();

    const int half = tid >> 7;        // 0/1: even/odd rows
    const int q = tid & 127;          // float4 column
    const float4* encp = (const float4*)(enc + ((size_t)b * NT + tbase) * NE);
    float ax = 0.f, ay = 0.f, az = 0.f, aw = 0.f;
    #pragma unroll 2
    for (int t = half; t < 250; t += 2) {
        float4 v = encp[(size_t)t * (NE / 4) + q];
        float a = at_s[t];
        ax += a * v.x; ay += a * v.y; az += a * v.z; aw += a * v.w;
    }
    float* cp = &ctx[(size_t)b * NE + q * 4];
    atomicAdd(cp + 0, ax);
    atomicAdd(cp + 1, ay);
    atomicAdd(cp + 2, az);
    atomicAdd(cp + 3, aw);
}

// ---------------------------------------------------------------------------
extern "C" void kernel_launch(void* const* d_in, const int* in_sizes, int n_in,
                              void* d_out, int out_size, void* d_ws, size_t ws_size,
                              hipStream_t stream)
{
    const float* dec    = (const float*)d_in[0];
    const float* enc    = (const float*)d_in[1];
    const float* prev   = (const float*)d_in[2];
    const int*   mask   = (const int*)d_in[3];
    const float* conv_w = (const float*)d_in[4];
    const float* W_enc  = (const float*)d_in[5];
    const float* W_dec  = (const float*)d_in[6];
    const float* W_loc  = (const float*)d_in[7];
    const float* v_w    = (const float*)d_in[8];

    float* out  = (float*)d_out;
    float* ctx  = out;             // [B,E]
    float* attn = out + NB * NE;   // [B,T]

    if (ws_size >= (size_t)WS_NEEDED) {
        // ---- MFMA path ----
        ushort_t* B_all = (ushort_t*)d_ws;
        float* dec_proj = (float*)((char*)d_ws + B_ALL_BYTES);

        hipMemsetAsync(dec_proj, 0, DECPROJ_BYTES, stream);
        pack_kernel<<<KC_N, 256, 0, stream>>>(W_enc, conv_w, W_loc, B_all);
        dec_proj_atomic_kernel<<<dim3(4, NB), 256, 0, stream>>>(dec, W_dec, dec_proj);
        energy_mfma_kernel<<<dim3(32, NB), 256, 0, stream>>>(
            enc, prev, mask, B_all, dec_proj, v_w, attn);
    } else {
        // ---- fp32 fallback (scratch carved from ctx region of d_out) ----
        float* dec_proj = ctx;
        float* Wc       = ctx + NB * NA;
        dec_proj_kernel<<<dim3(4, NB), 64, 0, stream>>>(dec, W_dec, dec_proj);
        wc_kernel<<<1, 256, 0, stream>>>(conv_w, W_loc, Wc);
        energy_kernel<<<dim3(32, NB), 256, 0, stream>>>(
            enc, prev, mask, W_enc, dec_proj, Wc, v_w, attn);
    }

    softmax_kernel<<<NB, 512, 0, stream>>>(attn, ctx);
    context_kernel<<<dim3(8, NB), 256, 0, stream>>>(enc, attn, ctx);
}